// Round 8
// baseline (103.579 us; speedup 1.0000x reference)
//
#include <hip/hip_runtime.h>
#include <hip/hip_fp16.h>

// CPDecoding (fp32 in/out): out[n] = sum_c fz[c][n] * fy[c][n] * fx[c][n]
// fz/fy/fx: 1-D linear interp (align_corners=True) of (C=96, R=512) tables.
//
// Round-8: one fused persistent kernel, no workspace, no prep launch.
//   - Coords are uniform[0,1) -> pos in [255.5, 511) -> only rows 255..511
//     (+pad 512) are ever read. Hot set = 258 rows x 96 fp16 x 3 tables,
//     row stride padded to 208 B -> 160,992 B: fits the 160 KiB LDS.
//   - Each of 256 persistent blocks (1/CU, 1024 thr) stages the hot rows
//     straight from the fp32 (C,R) sources (coalesced reads, ds_write_b16
//     transposed stores), then grid-strides over points.
//   - 8 lanes/point: ds_read_b128 (comps sl*8..+8) + ds_read_b64
//     (comps 64+sl*4..+4) per row; typed extern __shared__ keeps all table
//     reads in AS(3) (no flat loads). b128 reads are perfectly bank-balanced
//     (any 32-consecutive-dword window covers each bank once).
//   - r<255 safety path (never taken for valid inputs): cold scalar gather
//     from the fp32 sources, exec-masked off.
//   Known fixed overhead: harness re-poisons the 268 MB ws each iter
//   (~42 us fillBufferAligned) + input restore; not addressable here.

namespace {
constexpr int kC = 96;
constexpr int kR = 512;
constexpr int kBase = 255;        // first staged row
constexpr int kRows = 258;        // rows 255..512 (512 = copy of 511)
constexpr int kStrideH = 104;     // LDS row stride in halves (208 B, 16B mult)
constexpr int kTabH = kRows * kStrideH;          // halves per table in LDS
constexpr int kLdsBytes = 3 * kTabH * 2;         // 160,992 B
}  // namespace

typedef float vf3 __attribute__((ext_vector_type(3)));
typedef _Float16 vh2 __attribute__((ext_vector_type(2)));

__device__ __forceinline__ float dot2acc(__half2 a, __half2 b, float c) {
#if __has_builtin(__builtin_amdgcn_fdot2)
  return __builtin_amdgcn_fdot2(*(vh2*)&a, *(vh2*)&b, c, false);
#else
  return c + __low2float(a) * __low2float(b) +
         __high2float(a) * __high2float(b);
#endif
}

__device__ __forceinline__ __half2 u2h(unsigned u) { return *(__half2*)&u; }

__device__ __forceinline__ void prep_coord(float coord, int& i0, float& w) {
  float pos = (coord + 1.0f) * 0.5f * (float)(kR - 1);
  float fl = floorf(pos);
  fl = fminf(fmaxf(fl, 0.0f), (float)(kR - 1));
  i0 = (int)fl;
  w = pos - fl;
}

struct Frag { __half2 v[6]; };  // this lane's 12 lerped comps (one table)

__global__ __launch_bounds__(1024) void cp_decode_fused(
    const float* __restrict__ pts,  // (N,3), order x,y,z
    const float* __restrict__ lz, const float* __restrict__ ly,
    const float* __restrict__ lx, float* __restrict__ out, int n) {
  extern __shared__ __align__(16) __half smem_h[];

  // ---- stage rows [kBase, kBase+kRows) of all 3 tables: fp32 (C,R) -> LDS
  // consecutive threads take consecutive r (coalesced global reads).
  constexpr int perTab = kC * kRows;  // 24768
  for (int i = threadIdx.x; i < 3 * perTab; i += 1024) {
    int t = i / perTab;
    int rem = i - t * perTab;
    int c = rem / kRows;
    int r = rem - c * kRows;  // 0..257
    const float* src = (t == 0) ? lz : (t == 1) ? ly : lx;
    float v = src[c * kR + min(kBase + r, kR - 1)];
    smem_h[t * kTabH + r * kStrideH + c] = __float2half(v);
  }
  __syncthreads();

  int sl = threadIdx.x & 7;         // 8 lanes per point
  int lanePt = threadIdx.x >> 3;
  int ptsPerBlk = 1024 >> 3;        // 128
  int stride = gridDim.x * ptsPerBlk;

  for (int p = blockIdx.x * ptsPerBlk + lanePt; p < n; p += stride) {
    vf3 crd = *(const vf3*)(pts + 3 * (size_t)p);
    int i0[3];
    float w[3];
    prep_coord(crd.z, i0[0], w[0]);  // table 0 = z
    prep_coord(crd.y, i0[1], w[1]);  // table 1 = y
    prep_coord(crd.x, i0[2], w[2]);  // table 2 = x

    Frag f[3];
#pragma unroll
    for (int t = 0; t < 3; ++t) {
      int r = i0[t];
      int rl = r - kBase;
      int rc = min(max(rl, 0), kRows - 2);  // LDS row idx; rows rc, rc+1
      const __half* s0 = smem_h + t * kTabH + rc * kStrideH;
      // hot path: unconditional LDS reads (clamped, never OOB)
      uint4 a0 = *(const uint4*)(s0 + sl * 8);
      uint4 a1 = *(const uint4*)(s0 + kStrideH + sl * 8);
      uint2 b0 = *(const uint2*)(s0 + 64 + sl * 4);
      uint2 b1 = *(const uint2*)(s0 + kStrideH + 64 + sl * 4);
      __half2 w2 = __float2half2_rn(w[t]);
      const unsigned* u0 = (const unsigned*)&a0;
      const unsigned* u1 = (const unsigned*)&a1;
#pragma unroll
      for (int k = 0; k < 4; ++k)
        f[t].v[k] = __hfma2(w2, __hsub2(u2h(u1[k]), u2h(u0[k])), u2h(u0[k]));
      const unsigned* v0 = (const unsigned*)&b0;
      const unsigned* v1 = (const unsigned*)&b1;
#pragma unroll
      for (int k = 0; k < 2; ++k)
        f[t].v[4 + k] =
            __hfma2(w2, __hsub2(u2h(v1[k]), u2h(v0[k])), u2h(v0[k]));

      // cold safety path: r outside staged range (impossible for coords in
      // [0,1); exec-masked off). Scalar gather from the fp32 source.
      if (__builtin_expect(rl != rc, 0)) {
        const float* src = (t == 0) ? lz : (t == 1) ? ly : lx;
        int ra = min(max(r, 0), kR - 1);
        int rb = min(ra + 1, kR - 1);
        float fv[12];
#pragma unroll
        for (int k = 0; k < 8; ++k) {
          int c = sl * 8 + k;
          float a = src[c * kR + ra], b = src[c * kR + rb];
          fv[k] = fmaf(w[t], b - a, a);
        }
#pragma unroll
        for (int k = 0; k < 4; ++k) {
          int c = 64 + sl * 4 + k;
          float a = src[c * kR + ra], b = src[c * kR + rb];
          fv[8 + k] = fmaf(w[t], b - a, a);
        }
#pragma unroll
        for (int k = 0; k < 6; ++k)
          f[t].v[k] = __halves2half2(__float2half(fv[2 * k]),
                                     __float2half(fv[2 * k + 1]));
      }
    }

    float acc = 0.0f;
#pragma unroll
    for (int k = 0; k < 6; ++k)
      acc = dot2acc(__hmul2(f[0].v[k], f[1].v[k]), f[2].v[k], acc);

    acc += __shfl_xor(acc, 4);
    acc += __shfl_xor(acc, 2);
    acc += __shfl_xor(acc, 1);
    if (sl == 0) out[p] = acc;
  }
}

// ---------------- fallback path (LDS attribute rejected) ----------------
// R6-proven: fp16 transposed tables in ws + 8-lane global-gather decode.

namespace {
constexpr int kRPad = 513;
constexpr int kTabW = kRPad * kC;  // elements per (R+1,C) fp16 ws table
}  // namespace

__global__ __launch_bounds__(256) void prep_tables(
    const float* __restrict__ lz, const float* __restrict__ ly,
    const float* __restrict__ lx, __half* __restrict__ out) {
  int b = blockIdx.x;
  if (b >= 144) {
    for (int idx = threadIdx.x; idx < 3 * kC; idx += 256) {
      int t = idx / kC;
      int c = idx - t * kC;
      const float* src = (t == 0) ? lz : (t == 1) ? ly : lx;
      out[(size_t)t * kTabW + (size_t)512 * kC + c] =
          __float2half(src[c * kR + 511]);
    }
    return;
  }
  constexpr int TR = 64;
  constexpr int TC = 16;
  __shared__ float tile[TC][TR + 1];
  int t = b / 48;
  int rem = b - t * 48;
  int rt = rem / 6;
  int ct = rem - rt * 6;
  const float* src = (t == 0) ? lz : (t == 1) ? ly : lx;
  int r0 = rt * TR, c0 = ct * TC;
  int tx = threadIdx.x & 63;
  int ty = threadIdx.x >> 6;
  for (int cl = ty; cl < TC; cl += 4)
    tile[cl][tx] = src[(c0 + cl) * kR + r0 + tx];
  __syncthreads();
  int cx = threadIdx.x & 15;
  int rl = threadIdx.x >> 4;
#pragma unroll
  for (int pass = 0; pass < 4; ++pass) {
    int r = rl + 16 * pass;
    out[(size_t)t * kTabW + (size_t)(r0 + r) * kC + c0 + cx] =
        __float2half(tile[cx][r]);
  }
}

__global__ __launch_bounds__(256) void cp_decode_global(
    const float* __restrict__ pts, const __half* __restrict__ tabs,
    float* __restrict__ out, int n) {
  int tid = blockIdx.x * 256 + threadIdx.x;
  int p = tid >> 3;
  int sl = tid & 7;
  if (p >= n) return;
  vf3 crd = *(const vf3*)(pts + 3 * (size_t)p);
  int iz0, iy0, ix0;
  float wz, wy, wx;
  prep_coord(crd.z, iz0, wz);
  prep_coord(crd.y, iy0, wy);
  prep_coord(crd.x, ix0, wx);
  const __half* rz = tabs + (size_t)iz0 * kC;
  const __half* ry = tabs + kTabW + (size_t)iy0 * kC;
  const __half* rx = tabs + 2 * (size_t)kTabW + (size_t)ix0 * kC;
  float acc = 0.0f;
  const __half* rows[3] = {rz, ry, rx};
  float ws_[3] = {wz, wy, wx};
  __half2 fr[3][6];
#pragma unroll
  for (int t = 0; t < 3; ++t) {
    const __half* r0 = rows[t];
    uint4 a0 = *((const uint4*)r0 + sl);
    uint4 a1 = *((const uint4*)(r0 + kC) + sl);
    uint2 b0 = *((const uint2*)(r0 + 64) + sl);
    uint2 b1 = *((const uint2*)(r0 + kC + 64) + sl);
    __half2 w2 = __float2half2_rn(ws_[t]);
    const unsigned* u0 = (const unsigned*)&a0;
    const unsigned* u1 = (const unsigned*)&a1;
#pragma unroll
    for (int k = 0; k < 4; ++k)
      fr[t][k] = __hfma2(w2, __hsub2(u2h(u1[k]), u2h(u0[k])), u2h(u0[k]));
    const unsigned* v0 = (const unsigned*)&b0;
    const unsigned* v1 = (const unsigned*)&b1;
#pragma unroll
    for (int k = 0; k < 2; ++k)
      fr[t][4 + k] = __hfma2(w2, __hsub2(u2h(v1[k]), u2h(v0[k])), u2h(v0[k]));
  }
#pragma unroll
  for (int k = 0; k < 6; ++k)
    acc = dot2acc(__hmul2(fr[0][k], fr[1][k]), fr[2][k], acc);
  acc += __shfl_xor(acc, 4);
  acc += __shfl_xor(acc, 2);
  acc += __shfl_xor(acc, 1);
  if (sl == 0) out[p] = acc;
}

extern "C" void kernel_launch(void* const* d_in, const int* in_sizes, int n_in,
                              void* d_out, int out_size, void* d_ws, size_t ws_size,
                              hipStream_t stream) {
  const float* pts = (const float*)d_in[0];  // in_tensor (N,3)
  const float* lz  = (const float*)d_in[1];  // line_z (C,R)
  const float* ly  = (const float*)d_in[2];  // line_y
  const float* lx  = (const float*)d_in[3];  // line_x
  float* outp = (float*)d_out;
  int n = out_size;  // 786432 points

  hipError_t e = hipFuncSetAttribute(
      (const void*)cp_decode_fused,
      hipFuncAttributeMaxDynamicSharedMemorySize, kLdsBytes);
  if (e == hipSuccess) {
    cp_decode_fused<<<256, 1024, kLdsBytes, stream>>>(pts, lz, ly, lx, outp,
                                                      n);
  } else {
    __half* tabs = (__half*)d_ws;  // ~295 KB
    prep_tables<<<145, 256, 0, stream>>>(lz, ly, lx, tabs);
    long long threads = (long long)n * 8;
    int blocks = (int)((threads + 255) / 256);
    cp_decode_global<<<blocks, 256, 0, stream>>>(pts, tabs, outp, n);
  }
}